// Round 15
// baseline (98.566 us; speedup 1.0000x reference)
//
#include <hip/hip_runtime.h>
#include <hip/hip_fp16.h>

// GCN 2-layer + linear head on MI355X.
// out = relu(agg(relu(agg(X)@W1 + b1)@W2) + b2) @ Wl + bl
// agg(Y) = D^-1/2 (A+I) D^-1/2 Y  (commutes with the dense transform; layer 1
// aggregates X at 26 feats, layer 2 transforms first at 32 feats).
//
// Build: fixed 2176-slot region per 128-node bucket; per-chunk LDS hist -> one
// global atomicAdd per (chunk,bucket) range claim -> LDS-atomic scatter (edges
// register-cached between passes). Per-bucket degree/extents/node-sort with
// 4-ALIGNED per-node slot bases (scan over padded counts; oe = exact extents)
// + fp16 prescale (padded 64B rows).
// Gathers: 4-lane groups, one node/group, half8 (16B)/lane; slots read as
// aligned int4 (1 instr / 4 edges), unroll-8.
// Dense middle: MFMA (16x16x32 f16), fused behind gather1 (LDS handoff).
// Fragment maps (gfx950, HW-verified): A/B non-K index = lane&15, K-slice =
// (lane>>4)*8; C/D col=lane&15, row=(lane>>4)*4+reg.

#define TPB 256
#define NPB 128              // nodes per bucket (dstlow = 7 bits)
#define CAP 2176             // slots per bucket (avg fill 1534 + <=384 align pad; 6.6 sigma)
#define EPB 4096             // edges per scatter chunk (16 per thread, register-cached)
#define NBUCK_MAX 1024

typedef _Float16 half8 __attribute__((ext_vector_type(8)));
typedef float floatx4 __attribute__((ext_vector_type(4)));

// ---- scatter: LDS hist -> bulk range claim -> scatter; + W transpose (blk 0) --

__global__ __launch_bounds__(TPB) void scatter_direct_kernel(
        const int* __restrict__ src, const int* __restrict__ dst,
        int* __restrict__ bcnt, int* __restrict__ sortedb,
        const float* __restrict__ W1, const float* __restrict__ W2,
        float* __restrict__ W1t, float* __restrict__ W2t,
        int e, int nbuck) {
    __shared__ int lh[NBUCK_MAX];
    int t = threadIdx.x;
    for (int b = t; b < nbuck; b += TPB) lh[b] = 0;
    __syncthreads();
    int j0 = blockIdx.x * EPB;
    int j1 = min(e, j0 + EPB);
    // pass 1: load edges once, register-cache packed value + bucket, LDS hist
    int pk[16], bk[16];
#pragma unroll
    for (int q = 0; q < 16; ++q) {
        int j = j0 + t + q * TPB;
        int valid = (j < j1);
        int d = valid ? dst[j] : 0;
        int s = valid ? src[j] : 0;
        pk[q] = (s << 7) | (d & 127);
        bk[q] = valid ? (d >> 7) : -1;
        if (valid) atomicAdd(&lh[d >> 7], 1);
    }
    __syncthreads();
    for (int b = t; b < nbuck; b += TPB) {
        int c = lh[b];
        int base = c ? atomicAdd(&bcnt[b], c) : 0;   // bulk global claim
        lh[b] = b * CAP + base;                      // running write ptr
    }
    __syncthreads();
    // pass 2: scatter from registers (no global re-read)
#pragma unroll
    for (int q = 0; q < 16; ++q) {
        if (bk[q] >= 0) {
            int pos = atomicAdd(&lh[bk[q]], 1);      // LDS atomic only
            sortedb[pos] = pk[q];
        }
    }
    if (blockIdx.x == 0) {
        // W1t[64][32]: W1t[f*32+k] = W1[k*64+f] (k<26; pad 0). W2t[32][64].
        for (int q = t; q < 64 * 32; q += TPB) {
            int f = q >> 5, k = q & 31;
            W1t[q] = (k < 26) ? W1[k * 64 + f] : 0.0f;
        }
        for (int q = t; q < 32 * 64; q += TPB) {
            int f = q >> 6, k = q & 63;
            W2t[q] = W2[k * 32 + f];
        }
    }
}

// ---- per bucket: degrees -> dis/extents (4-aligned bases), node-sort, prescale

__global__ __launch_bounds__(TPB) void bucket_sort_fill_kernel(
        const int* __restrict__ sortedb, const int* __restrict__ bcnt,
        const float* __restrict__ x,
        int* __restrict__ slot, float* __restrict__ dis, int2* __restrict__ oe,
        __half* __restrict__ xs, int n, int nbuck) {
    __shared__ int c[NPB];
    __shared__ int ptr[NPB];
    __shared__ float sdis[NPB];
    int b = blockIdx.x, t = threadIdx.x;
    if (t < NPB) c[t] = 0;
    __syncthreads();
    int start = b * CAP;
    int end = start + bcnt[b];
    for (int j = start + t; j < end; j += TPB)
        atomicAdd(&c[sortedb[j] & 127], 1);
    __syncthreads();
    int mycnt = (t < NPB) ? c[t] : 0;
    int mypad = (mycnt + 3) & ~3;            // 4-aligned allocation
    if (t < NPB) c[t] = mypad;
    __syncthreads();
    // inclusive Hillis-Steele scan over padded counts
    for (int d = 1; d < NPB; d <<= 1) {
        int v = 0;
        if (t < NPB && t >= d) v = c[t - d];
        __syncthreads();
        if (t < NPB) c[t] += v;
        __syncthreads();
    }
    if (t < NPB) {
        int excl = c[t] - mypad;             // 4-aligned (sum of multiples of 4)
        ptr[t] = excl;
        float dv = rsqrtf((float)mycnt + 1.0f);
        sdis[t] = dv;
        int g = b * NPB + t;
        if (g < n) {
            dis[g] = dv;
            oe[g] = make_int2(start + excl, start + excl + mycnt);  // exact extents
        }
    }
    __syncthreads();
    for (int j = start + t; j < end; j += TPB) {
        int w = sortedb[j];
        int pos = atomicAdd(&ptr[w & 127], 1);  // LDS atomic only
        slot[start + pos] = w >> 7;
    }
    // fused prescale (fp16 padded 64B rows)
    int base = b * NPB;
    for (int i = t; i < NPB * 32; i += TPB) {
        int r = i >> 5, lane = i & 31;
        int g = base + r;
        if (g < n)
            xs[(size_t)g * 32 + lane] = __float2half(
                (lane < 26) ? sdis[r] * x[(size_t)g * 26 + lane] : 0.0f);
    }
}

// ---- fused gather1 + MFMA dense middle --------------------------------------
// Phase A: 64x 4-lane groups, one node each; half8/lane; int4 slot loads, unroll-8.
// Phase B: per-wave 16-node tile MFMA; h1 -> per-wave LDS; fp16 store.

__global__ __launch_bounds__(TPB) void gather1_dense_kernel(
        const __half* __restrict__ xs, const int2* __restrict__ oe,
        const int* __restrict__ slot, const float* __restrict__ dis,
        const float* __restrict__ W1t, const float* __restrict__ b1,
        const float* __restrict__ W2t, __half* __restrict__ xw2s, int n) {
    __shared__ _Float16 ssum[64][40];     // agg(X) tile: 64 nodes x 32 f (+8 pad)
    __shared__ _Float16 shh[4][16][72];   // h1: per-wave 16x64 (+8 pad)
    __shared__ _Float16 sho[4][16][40];   // out: per-wave 16x32 (+8 pad)
    int t = threadIdx.x;
    int node0 = blockIdx.x * 64;
    const _Float16* xsp = (const _Float16*)xs;

    // ---- phase A: gather (4 lanes per node, 8 feats per lane)
    {
        int g = t >> 2;              // 0..63 : node group
        int fl = (t & 3) * 8;        // feature chunk base
        int node = node0 + g;
        float accf[8];
#pragma unroll
        for (int k = 0; k < 8; ++k) accf[k] = 0.0f;
        if (node < n) {
            half8 ownv = *(const half8*)(xsp + (size_t)node * 32 + fl);
#pragma unroll
            for (int k = 0; k < 8; ++k) accf[k] = (float)ownv[k];
            int2 se = oe[node];
            int j = se.x, end = se.y;    // j is 4-aligned by construction
            for (; j + 7 < end; j += 8) {
                int4 sa = *(const int4*)(slot + j);
                int4 sb = *(const int4*)(slot + j + 4);
                half8 v0 = *(const half8*)(xsp + (size_t)sa.x * 32 + fl);
                half8 v1 = *(const half8*)(xsp + (size_t)sa.y * 32 + fl);
                half8 v2 = *(const half8*)(xsp + (size_t)sa.z * 32 + fl);
                half8 v3 = *(const half8*)(xsp + (size_t)sa.w * 32 + fl);
                half8 v4 = *(const half8*)(xsp + (size_t)sb.x * 32 + fl);
                half8 v5 = *(const half8*)(xsp + (size_t)sb.y * 32 + fl);
                half8 v6 = *(const half8*)(xsp + (size_t)sb.z * 32 + fl);
                half8 v7 = *(const half8*)(xsp + (size_t)sb.w * 32 + fl);
#pragma unroll
                for (int k = 0; k < 8; ++k)
                    accf[k] += (((float)v0[k] + (float)v1[k]) + ((float)v2[k] + (float)v3[k]))
                             + (((float)v4[k] + (float)v5[k]) + ((float)v6[k] + (float)v7[k]));
            }
            if (j + 3 < end) {
                int4 sa = *(const int4*)(slot + j);
                half8 v0 = *(const half8*)(xsp + (size_t)sa.x * 32 + fl);
                half8 v1 = *(const half8*)(xsp + (size_t)sa.y * 32 + fl);
                half8 v2 = *(const half8*)(xsp + (size_t)sa.z * 32 + fl);
                half8 v3 = *(const half8*)(xsp + (size_t)sa.w * 32 + fl);
#pragma unroll
                for (int k = 0; k < 8; ++k)
                    accf[k] += ((float)v0[k] + (float)v1[k]) + ((float)v2[k] + (float)v3[k]);
                j += 4;
            }
            for (; j < end; ++j) {
                int s = slot[j];
                half8 v = *(const half8*)(xsp + (size_t)s * 32 + fl);
#pragma unroll
                for (int k = 0; k < 8; ++k) accf[k] += (float)v[k];
            }
        }
        half8 o;
#pragma unroll
        for (int k = 0; k < 8; ++k) o[k] = (_Float16)accf[k];
        *(half8*)&ssum[g][fl] = o;
    }
    __syncthreads();

    // ---- phase B: MFMA dense middle
    int w = t >> 6, l = t & 63;
    int tnode0 = node0 + w * 16;
    int lm = l & 15;           // A/B non-K index
    int lk = l >> 4;           // K-slice id 0..3

    half8 a1 = *(const half8*)&ssum[w * 16 + lm][lk * 8];

    float dvv[4];
#pragma unroll
    for (int r = 0; r < 4; ++r) {
        int nd = tnode0 + lk * 4 + r;
        dvv[r] = dis[nd < n ? nd : (n - 1)];
    }

    // layer 1: 4 f-tiles of 16
#pragma unroll
    for (int T = 0; T < 4; ++T) {
        const float* bp = W1t + (size_t)(T * 16 + lm) * 32 + lk * 8;
        float4 bv0 = *(const float4*)bp;
        float4 bv1 = *(const float4*)(bp + 4);
        half8 bf;
        bf[0] = (_Float16)bv0.x; bf[1] = (_Float16)bv0.y;
        bf[2] = (_Float16)bv0.z; bf[3] = (_Float16)bv0.w;
        bf[4] = (_Float16)bv1.x; bf[5] = (_Float16)bv1.y;
        bf[6] = (_Float16)bv1.z; bf[7] = (_Float16)bv1.w;
        floatx4 c = {0.0f, 0.0f, 0.0f, 0.0f};
        c = __builtin_amdgcn_mfma_f32_16x16x32_f16(a1, bf, c, 0, 0, 0);
        float bias = b1[T * 16 + lm];
#pragma unroll
        for (int r = 0; r < 4; ++r) {
            float h = fmaxf(dvv[r] * c[r] + bias, 0.0f);
            shh[w][lk * 4 + r][T * 16 + lm] = (_Float16)h;
        }
    }

    // layer 2: A2 from per-wave LDS tile (node=lm), 2 K-steps x 2 f-tiles
    half8 a2k0 = *(const half8*)&shh[w][lm][lk * 8];
    half8 a2k1 = *(const half8*)&shh[w][lm][32 + lk * 8];
#pragma unroll
    for (int T = 0; T < 2; ++T) {
        const float* bp0 = W2t + (size_t)(T * 16 + lm) * 64 + lk * 8;
        const float* bp1 = bp0 + 32;
        float4 c0 = *(const float4*)bp0;
        float4 c1 = *(const float4*)(bp0 + 4);
        float4 c2 = *(const float4*)bp1;
        float4 c3 = *(const float4*)(bp1 + 4);
        half8 bf0, bf1;
        bf0[0] = (_Float16)c0.x; bf0[1] = (_Float16)c0.y;
        bf0[2] = (_Float16)c0.z; bf0[3] = (_Float16)c0.w;
        bf0[4] = (_Float16)c1.x; bf0[5] = (_Float16)c1.y;
        bf0[6] = (_Float16)c1.z; bf0[7] = (_Float16)c1.w;
        bf1[0] = (_Float16)c2.x; bf1[1] = (_Float16)c2.y;
        bf1[2] = (_Float16)c2.z; bf1[3] = (_Float16)c2.w;
        bf1[4] = (_Float16)c3.x; bf1[5] = (_Float16)c3.y;
        bf1[6] = (_Float16)c3.z; bf1[7] = (_Float16)c3.w;
        floatx4 acc = {0.0f, 0.0f, 0.0f, 0.0f};
        acc = __builtin_amdgcn_mfma_f32_16x16x32_f16(a2k0, bf0, acc, 0, 0, 0);
        acc = __builtin_amdgcn_mfma_f32_16x16x32_f16(a2k1, bf1, acc, 0, 0, 0);
#pragma unroll
        for (int r = 0; r < 4; ++r)
            sho[w][lk * 4 + r][T * 16 + lm] = (_Float16)(dvv[r] * acc[r]);
    }

    // coalesced store: lane -> node_local l>>2, f2-chunk (l&3)*8
    int nl = l >> 2, fc = (l & 3) * 8;
    int gnode = tnode0 + nl;
    if (gnode < n) {
        half8 v = *(const half8*)&sho[w][nl][fc];
        *(half8*)((_Float16*)xw2s + (size_t)gnode * 32 + fc) = v;
    }
}

// ---- layer 2 gather + bias + relu + head (4-lane groups, int4 slots) ---------

__global__ __launch_bounds__(TPB) void gather2_head_kernel(
        const __half* __restrict__ xw2s, const float* __restrict__ dis,
        const int2* __restrict__ oe, const int* __restrict__ slot,
        const float* __restrict__ b2, const float* __restrict__ Wl,
        const float* __restrict__ bl, float* __restrict__ out, int n) {
    int t = threadIdx.x;
    int g = t >> 2;              // 0..63 : node group
    int fl = (t & 3) * 8;        // feature chunk base
    int node = blockIdx.x * 64 + g;
    if (node >= n) return;
    const _Float16* xp = (const _Float16*)xw2s;

    float accf[8];
    half8 ownv = *(const half8*)(xp + (size_t)node * 32 + fl);
#pragma unroll
    for (int k = 0; k < 8; ++k) accf[k] = (float)ownv[k];
    int2 se = oe[node];
    int j = se.x, end = se.y;    // j is 4-aligned
    for (; j + 7 < end; j += 8) {
        int4 sa = *(const int4*)(slot + j);
        int4 sb = *(const int4*)(slot + j + 4);
        half8 v0 = *(const half8*)(xp + (size_t)sa.x * 32 + fl);
        half8 v1 = *(const half8*)(xp + (size_t)sa.y * 32 + fl);
        half8 v2 = *(const half8*)(xp + (size_t)sa.z * 32 + fl);
        half8 v3 = *(const half8*)(xp + (size_t)sa.w * 32 + fl);
        half8 v4 = *(const half8*)(xp + (size_t)sb.x * 32 + fl);
        half8 v5 = *(const half8*)(xp + (size_t)sb.y * 32 + fl);
        half8 v6 = *(const half8*)(xp + (size_t)sb.z * 32 + fl);
        half8 v7 = *(const half8*)(xp + (size_t)sb.w * 32 + fl);
#pragma unroll
        for (int k = 0; k < 8; ++k)
            accf[k] += (((float)v0[k] + (float)v1[k]) + ((float)v2[k] + (float)v3[k]))
                     + (((float)v4[k] + (float)v5[k]) + ((float)v6[k] + (float)v7[k]));
    }
    if (j + 3 < end) {
        int4 sa = *(const int4*)(slot + j);
        half8 v0 = *(const half8*)(xp + (size_t)sa.x * 32 + fl);
        half8 v1 = *(const half8*)(xp + (size_t)sa.y * 32 + fl);
        half8 v2 = *(const half8*)(xp + (size_t)sa.z * 32 + fl);
        half8 v3 = *(const half8*)(xp + (size_t)sa.w * 32 + fl);
#pragma unroll
        for (int k = 0; k < 8; ++k)
            accf[k] += ((float)v0[k] + (float)v1[k]) + ((float)v2[k] + (float)v3[k]);
        j += 4;
    }
    for (; j < end; ++j) {
        int s = slot[j];
        half8 v = *(const half8*)(xp + (size_t)s * 32 + fl);
#pragma unroll
        for (int k = 0; k < 8; ++k) accf[k] += (float)v[k];
    }

    float dv = dis[node];
    float4 bq0 = *(const float4*)(b2 + fl);
    float4 bq1 = *(const float4*)(b2 + fl + 4);
    float4 wq0 = *(const float4*)(Wl + fl);
    float4 wq1 = *(const float4*)(Wl + fl + 4);
    float bb[8] = {bq0.x, bq0.y, bq0.z, bq0.w, bq1.x, bq1.y, bq1.z, bq1.w};
    float wl[8] = {wq0.x, wq0.y, wq0.z, wq0.w, wq1.x, wq1.y, wq1.z, wq1.w};
    float c = 0.0f;
#pragma unroll
    for (int k = 0; k < 8; ++k) {
        float v = fmaxf(dv * accf[k] + bb[k], 0.0f);
        c += v * wl[k];
    }
    c += __shfl_xor(c, 1);
    c += __shfl_xor(c, 2);
    if ((t & 3) == 0) out[node] = c + bl[0];
}

// ---- host ------------------------------------------------------------------

extern "C" void kernel_launch(void* const* d_in, const int* in_sizes, int n_in,
                              void* d_out, int out_size, void* d_ws, size_t ws_size,
                              hipStream_t stream) {
    const float* x  = (const float*)d_in[0];
    const int*   ei = (const int*)d_in[1];
    const float* W1 = (const float*)d_in[2];
    const float* b1 = (const float*)d_in[3];
    const float* W2 = (const float*)d_in[4];
    const float* b2 = (const float*)d_in[5];
    const float* Wl = (const float*)d_in[6];
    const float* bl = (const float*)d_in[7];
    float* out = (float*)d_out;

    const int n = in_sizes[0] / 26;
    const int e = in_sizes[1] / 2;
    const int* src = ei;
    const int* dst = ei + e;

    const int nbuck = (n + NPB - 1) / NPB;   // 782 (<= NBUCK_MAX)
    const int eb    = (e + EPB - 1) / EPB;   // 293 scatter chunks

    auto align_up = [](size_t v) { return (v + 255) & ~(size_t)255; };
    char* p = (char*)d_ws;
    int*    bcnt    = (int*)p;     p += align_up((size_t)nbuck * 4);
    int*    sortedb = (int*)p;     p += align_up(((size_t)nbuck * CAP + 4096) * 4);
    int*    slot    = (int*)p;     p += align_up(((size_t)nbuck * CAP + 4096) * 4);
    float*  dis     = (float*)p;   p += align_up((size_t)n * 4);
    int2*   oe      = (int2*)p;    p += align_up((size_t)n * 8);
    float*  W1t     = (float*)p;   p += align_up(64 * 32 * 4);
    float*  W2t     = (float*)p;   p += align_up(32 * 64 * 4);
    __half* xs      = (__half*)p;  p += align_up((size_t)n * 32 * 2);
    __half* xw2s    = (__half*)p;  p += align_up((size_t)n * 32 * 2);

    // 1) build: zero bucket counters, scatter with bulk range claiming
    hipMemsetAsync(bcnt, 0, (size_t)nbuck * 4, stream);
    scatter_direct_kernel<<<eb, TPB, 0, stream>>>(src, dst, bcnt, sortedb,
                                                  W1, W2, W1t, W2t, e, nbuck);
    bucket_sort_fill_kernel<<<nbuck, TPB, 0, stream>>>(sortedb, bcnt, x, slot,
                                                       dis, oe, xs, n, nbuck);

    // 2) fused layer-1 gather + MFMA dense middle
    gather1_dense_kernel<<<(n + 63) / 64, TPB, 0, stream>>>(xs, oe, slot, dis,
                                                            W1t, b1, W2t, xw2s, n);

    // 3) layer 2 gather + bias + relu + head (fused)
    gather2_head_kernel<<<(n + 63) / 64, TPB, 0, stream>>>(xw2s, dis, oe, slot,
                                                           b2, Wl, bl, out, n);
}